// Round 10
// baseline (294.645 us; speedup 1.0000x reference)
//
#include <hip/hip_runtime.h>
#include <math.h>

#define NT 32768
#define DIM 2048
#define NE 64
#define RSCALE 2.5f
#define REPS 1e-20f
#define KC 32
#define NSPLIT 4
#define KSEG (DIM / NSPLIT)     // 512 K per block
#define NCHB (KSEG / KC)        // 16 chunks per block
#define TOK 64

// single-buffered LDS limb planes:
//   HL[3][64 tok][4 slots x 16B] : 0     .. 12287
//   WL[3][64 exp][4 slots x 16B] : 12288 .. 24575
#define WL_OFF 12288
#define ARENA 24576

typedef __attribute__((ext_vector_type(8))) short short8x;
typedef __attribute__((ext_vector_type(4))) float f32x4;
typedef __attribute__((ext_vector_type(4))) unsigned int uint4x;

// fp64 logit partials per K-split: wsbuf[split][token][expert]
__device__ double wsbuf[NSPLIT][NT][NE];

// pack hi16 of two fp32 into one dword (low half = even element)
#define PACKHI(odd, even) __builtin_amdgcn_perm((odd), (even), 0x07060302u)

__device__ __forceinline__ void decomp4(f32x4 x, unsigned int o[6]) {
    unsigned int u0 = __float_as_uint(x.x), u1 = __float_as_uint(x.y);
    unsigned int u2 = __float_as_uint(x.z), u3 = __float_as_uint(x.w);
    o[0] = PACKHI(u1, u0); o[1] = PACKHI(u3, u2);
    float r0 = x.x - __uint_as_float(u0 & 0xffff0000u);
    float r1 = x.y - __uint_as_float(u1 & 0xffff0000u);
    float r2 = x.z - __uint_as_float(u2 & 0xffff0000u);
    float r3 = x.w - __uint_as_float(u3 & 0xffff0000u);
    unsigned int v0 = __float_as_uint(r0), v1 = __float_as_uint(r1);
    unsigned int v2 = __float_as_uint(r2), v3 = __float_as_uint(r3);
    o[2] = PACKHI(v1, v0); o[3] = PACKHI(v3, v2);
    float s0 = r0 - __uint_as_float(v0 & 0xffff0000u);
    float s1 = r1 - __uint_as_float(v1 & 0xffff0000u);
    float s2 = r2 - __uint_as_float(v2 & 0xffff0000u);
    float s3 = r3 - __uint_as_float(v3 & 0xffff0000u);
    o[4] = PACKHI(__float_as_uint(s1), __float_as_uint(s0));
    o[5] = PACKHI(__float_as_uint(s3), __float_as_uint(s2));
}

__device__ __forceinline__ void decomp8(f32x4 a, f32x4 b,
                                        short8x* f0, short8x* f1, short8x* f2) {
    unsigned int oa[6], ob[6];
    decomp4(a, oa); decomp4(b, ob);
    uint4x t0 = {oa[0], oa[1], ob[0], ob[1]};
    uint4x t1 = {oa[2], oa[3], ob[2], ob[3]};
    uint4x t2 = {oa[4], oa[5], ob[4], ob[5]};
    *f0 = __builtin_bit_cast(short8x, t0);
    *f1 = __builtin_bit_cast(short8x, t1);
    *f2 = __builtin_bit_cast(short8x, t2);
}

// lgkm-only barrier: commit LDS ops, sync, leave global loads in flight (counted vmcnt)
#define BARRIER() do { \
    asm volatile("s_waitcnt lgkmcnt(0)" ::: "memory"); \
    __builtin_amdgcn_s_barrier(); \
    __builtin_amdgcn_sched_barrier(0); \
} while (0)

// issue chunk (KOFF) global loads (H octet + W octet) into named reg slot
#define STAGE_ISSUE(HA, HB, WA, WB, KOFF) do { \
    HA = *(const f32x4*)(hgsrc + (KOFF));     \
    HB = *(const f32x4*)(hgsrc + (KOFF) + 4); \
    WA = *(const f32x4*)(wgsrc + (KOFF));     \
    WB = *(const f32x4*)(wgsrc + (KOFF) + 4); \
} while (0)

// decompose staged regs and write H+W limb planes (single buffer)
#define STAGE_WRITE(HA, HB, WA, WB) do { \
    short8x f0_, f1_, f2_; \
    decomp8(HA, HB, &f0_, &f1_, &f2_); \
    *(short8x*)(arena + 0 * 4096 + soff) = f0_; \
    *(short8x*)(arena + 1 * 4096 + soff) = f1_; \
    *(short8x*)(arena + 2 * 4096 + soff) = f2_; \
    decomp8(WA, WB, &f0_, &f1_, &f2_); \
    *(short8x*)(arena + WL_OFF + 0 * 4096 + soff) = f0_; \
    *(short8x*)(arena + WL_OFF + 1 * 4096 + soff) = f1_; \
    *(short8x*)(arena + WL_OFF + 2 * 4096 + soff) = f2_; \
} while (0)

// wave = 32 tok x 32 exp = 2x2 16x16 tiles; 12 b128 reads feed 24 MFMAs.
// Per-tile MFMA order identical to the passing kernels (bit-identical tile partials).
#define COMPUTE() do { \
    const char* hb = arena; \
    const char* wb = arena + WL_OFF; \
    short8x a0[2], a1[2], a2[2]; \
    _Pragma("unroll") \
    for (int tt = 0; tt < 2; ++tt) { \
        const int t_ = wr * 32 + tt * 16 + l15; \
        const int ro_ = t_ * 64 + ((g ^ ((t_ >> 1) & 3)) << 4); \
        a0[tt] = *(const short8x*)(hb + 0 * 4096 + ro_); \
        a1[tt] = *(const short8x*)(hb + 1 * 4096 + ro_); \
        a2[tt] = *(const short8x*)(hb + 2 * 4096 + ro_); \
    } \
    _Pragma("unroll") \
    for (int et = 0; et < 2; ++et) { \
        const int e_ = wc * 32 + et * 16 + l15; \
        const int ro_ = e_ * 64 + ((g ^ ((e_ >> 1) & 3)) << 4); \
        short8x b0 = *(const short8x*)(wb + 0 * 4096 + ro_); \
        short8x b1 = *(const short8x*)(wb + 1 * 4096 + ro_); \
        short8x b2 = *(const short8x*)(wb + 2 * 4096 + ro_); \
        _Pragma("unroll") \
        for (int tt = 0; tt < 2; ++tt) { \
            Cm[tt][et] = __builtin_amdgcn_mfma_f32_16x16x32_bf16(a0[tt], b0, Cm[tt][et], 0, 0, 0); \
            Cc[tt][et] = __builtin_amdgcn_mfma_f32_16x16x32_bf16(a1[tt], b0, Cc[tt][et], 0, 0, 0); \
            Cc[tt][et] = __builtin_amdgcn_mfma_f32_16x16x32_bf16(a2[tt], b0, Cc[tt][et], 0, 0, 0); \
            Cc[tt][et] = __builtin_amdgcn_mfma_f32_16x16x32_bf16(a0[tt], b1, Cc[tt][et], 0, 0, 0); \
            Cc[tt][et] = __builtin_amdgcn_mfma_f32_16x16x32_bf16(a1[tt], b1, Cc[tt][et], 0, 0, 0); \
            Cc[tt][et] = __builtin_amdgcn_mfma_f32_16x16x32_bf16(a0[tt], b2, Cc[tt][et], 0, 0, 0); \
        } \
    } \
} while (0)

#define DRAIN do { \
    _Pragma("unroll") \
    for (int tt = 0; tt < 2; ++tt) \
        _Pragma("unroll") \
        for (int et = 0; et < 2; ++et) { \
            _Pragma("unroll") \
            for (int r = 0; r < 4; ++r) \
                md[tt][et][r] += (double)Cm[tt][et][r] + (double)Cc[tt][et][r]; \
            Cm[tt][et] = (f32x4)0.0f; Cc[tt][et] = (f32x4)0.0f; \
        } \
} while (0)

// GEMM partial kernel: grid (512 token-blocks, 4 K-splits) x 256 threads (4 waves).
// Block = 64 tok x 64 exp x 512 K; single-buffered LDS (24.6 KB -> 5+ blocks/CU);
// depth-2 reg prefetch; lgkm-only barriers. Writes fp64 partials to wsbuf.
__global__ __launch_bounds__(256, 5) void router_gemm(
    const float* __restrict__ H,
    const float* __restrict__ W)
{
    __shared__ __align__(16) char arena[ARENA];

    const int tid  = threadIdx.x;
    const int lane = tid & 63;
    const int w    = __builtin_amdgcn_readfirstlane(tid >> 6);
    const int l15  = lane & 15, g = lane >> 4;
    const size_t tb = (size_t)blockIdx.x * TOK;
    const int split = blockIdx.y;
    const int kbase = split * KSEG;

    // staging role: row = tid>>2 (0..63), k-octet = tid&3; thread stages H row AND W row
    const int srow = tid >> 2;
    const int sq   = tid & 3;
    const float* hgsrc = H + (tb + (size_t)srow) * DIM + kbase + sq * 8;
    const float* wgsrc = W + (size_t)srow * DIM + kbase + sq * 8;
    const int soff = srow * 64 + ((sq ^ ((srow >> 1) & 3)) << 4);

    // compute role: wave quadrant (32 tok x 32 exp)
    const int wr = w & 1, wc = w >> 1;

    f32x4 Cm[2][2], Cc[2][2];
    double md[2][2][4];
    #pragma unroll
    for (int tt = 0; tt < 2; ++tt)
        #pragma unroll
        for (int et = 0; et < 2; ++et) {
            Cm[tt][et] = (f32x4)0.0f; Cc[tt][et] = (f32x4)0.0f;
            #pragma unroll
            for (int r = 0; r < 4; ++r) md[tt][et][r] = 0.0;
        }

    f32x4 hA0, hA1, wA0, wA1, hB0, hB1, wB0, wB1;

    // prologue: issue chunks 0,1; write chunk 0
    STAGE_ISSUE(hA0, hA1, wA0, wA1, 0);
    STAGE_ISSUE(hB0, hB1, wB0, wB1, KC);
    STAGE_WRITE(hA0, hA1, wA0, wA1);
    BARRIER();

    for (int chb = 0; chb < NCHB; chb += 2) {
        // even chunk chb (in buf)
        COMPUTE();
        if (chb + 2 < NCHB) STAGE_ISSUE(hA0, hA1, wA0, wA1, (chb + 2) * KC);
        BARRIER();                                  // reads done
        STAGE_WRITE(hB0, hB1, wB0, wB1);            // chunk chb+1 -> buf
        BARRIER();                                  // writes visible

        // odd chunk chb+1
        COMPUTE();
        if (chb + 3 < NCHB) STAGE_ISSUE(hB0, hB1, wB0, wB1, (chb + 3) * KC);
        if (((chb + 1) & 7) == 7) DRAIN;            // local chunks 7, 15
        BARRIER();                                  // reads done
        if (chb + 2 < NCHB) STAGE_WRITE(hA0, hA1, wA0, wA1);
        BARRIER();                                  // writes visible
    }

    // write fp64 partials (C layout: t = wr*32+tt*16+g*4+r, e = wc*32+et*16+l15)
    #pragma unroll
    for (int tt = 0; tt < 2; ++tt)
        #pragma unroll
        for (int et = 0; et < 2; ++et)
            #pragma unroll
            for (int r = 0; r < 4; ++r)
                wsbuf[split][tb + wr * 32 + tt * 16 + g * 4 + r]
                     [wc * 32 + et * 16 + l15] = md[tt][et][r];
}

// reducer: sum splits in order (left fold), sigmoid, grouped top-k.
// 512 blocks x 256 threads; lane = expert (coalesced fp64 reads).
__global__ __launch_bounds__(256) void router_topk(
    const float* __restrict__ B,
    float* __restrict__ out)
{
    __shared__ float scf[TOK * 65];
    __shared__ float bsf[NE];

    const int tid = threadIdx.x;
    const size_t tb = (size_t)blockIdx.x * TOK;

    if (tid < NE) bsf[tid] = B[tid];

    const int e  = tid & 63;
    const int t4 = tid >> 6;
    #pragma unroll
    for (int pass = 0; pass < 16; ++pass) {
        const int t = pass * 4 + t4;
        const size_t token = tb + t;
        double m = ((wsbuf[0][token][e] + wsbuf[1][token][e])
                  + wsbuf[2][token][e]) + wsbuf[3][token][e];
        scf[t * 65 + e] = 1.0f / (1.0f + expf(-(float)m));
    }
    __syncthreads();

    // grouped top-k, one token per active thread (64 tokens over 4 waves)
    if ((tid & 3) == 0) {
        const int t = tid >> 2;
        const float* sc = &scf[t * 65];
        float gs[8];
        #pragma unroll
        for (int gg = 0; gg < 8; ++gg) {
            float m1 = -1e30f, m2 = -1e30f;
            #pragma unroll
            for (int j = 0; j < 8; ++j) {
                float v = sc[gg * 8 + j] + bsf[gg * 8 + j];
                if (v > m1) { m2 = m1; m1 = v; }
                else if (v > m2) { m2 = v; }
            }
            gs[gg] = m1 + m2;
        }
        unsigned gmask = 0;
        for (int i = 0; i < 4; ++i) {
            float best = -1e30f; int bg = 0;
            for (int gg = 0; gg < 8; ++gg)
                if (!((gmask >> gg) & 1u) && gs[gg] > best) { best = gs[gg]; bg = gg; }
            gmask |= 1u << bg;
        }
        unsigned long long picked = 0ull;
        int   idxs[8];
        float wts[8];
        float wsum = 0.0f;
        for (int i = 0; i < 8; ++i) {
            float best = -1e30f; int bi = 0;
            for (int ee = 0; ee < 64; ++ee) {
                if ((picked >> ee) & 1ull) continue;
                float v = ((gmask >> (ee >> 3)) & 1u) ? (sc[ee] + bsf[ee]) : 0.0f;
                if (v > best) { best = v; bi = ee; }
            }
            picked |= 1ull << bi;
            idxs[i] = bi;
            wts[i] = sc[bi];
            wsum += sc[bi];
        }
        const float scale = RSCALE / (wsum + REPS);
        const size_t token = tb + t;
        #pragma unroll
        for (int i = 0; i < 8; ++i) {
            out[token * 8 + i] = (float)idxs[i];
            out[(size_t)NT * 8 + token * 8 + i] = wts[i] * scale;
        }
    }
}

extern "C" void kernel_launch(void* const* d_in, const int* in_sizes, int n_in,
                              void* d_out, int out_size, void* d_ws, size_t ws_size,
                              hipStream_t stream) {
    (void)in_sizes; (void)n_in; (void)out_size; (void)d_ws; (void)ws_size;
    const float* H = (const float*)d_in[0];
    const float* W = (const float*)d_in[1];
    const float* B = (const float*)d_in[2];
    float* out = (float*)d_out;
    router_gemm<<<dim3(NT / TOK, NSPLIT), dim3(256), 0, stream>>>(H, W);
    router_topk<<<dim3(NT / TOK), dim3(256), 0, stream>>>(B, out);
}

// Round 11
// 155.263 us; speedup vs baseline: 1.8977x; 1.8977x over previous
//
#include <hip/hip_runtime.h>
#include <math.h>

#define NT 32768
#define DIM 2048
#define NE 64
#define RSCALE 2.5f
#define REPS 1e-20f
#define KC 32
#define NCHG 32                  // chunks per K-group (half of 64)
#define KSEG (NCHG * KC)         // 1024 K per group
#define TOK 64

// LDS layout (bytes):
//   group arenas: grp g at [g*24576, g*24576+24576): HL[3][64][64B] + WL[3][64][64B]
//   epilogue alias: mdbuf f64[16][256] at [0, 32768), Sc f32[64][65] at [32768, 49408)
//   Bs f32[64] at [49408, 49664)  (never aliased)
#define GRP_ARENA 24576
#define WL_OFF 12288
#define MD_OFF 0
#define SC_OFF 32768
#define BS_OFF 49408
#define ARENA 49664

typedef __attribute__((ext_vector_type(8))) short short8x;
typedef __attribute__((ext_vector_type(4))) float f32x4;
typedef __attribute__((ext_vector_type(4))) unsigned int uint4x;

// pack hi16 of two fp32 into one dword (low half = even element)
#define PACKHI(odd, even) __builtin_amdgcn_perm((odd), (even), 0x07060302u)

__device__ __forceinline__ void decomp4(f32x4 x, unsigned int o[6]) {
    unsigned int u0 = __float_as_uint(x.x), u1 = __float_as_uint(x.y);
    unsigned int u2 = __float_as_uint(x.z), u3 = __float_as_uint(x.w);
    o[0] = PACKHI(u1, u0); o[1] = PACKHI(u3, u2);
    float r0 = x.x - __uint_as_float(u0 & 0xffff0000u);
    float r1 = x.y - __uint_as_float(u1 & 0xffff0000u);
    float r2 = x.z - __uint_as_float(u2 & 0xffff0000u);
    float r3 = x.w - __uint_as_float(u3 & 0xffff0000u);
    unsigned int v0 = __float_as_uint(r0), v1 = __float_as_uint(r1);
    unsigned int v2 = __float_as_uint(r2), v3 = __float_as_uint(r3);
    o[2] = PACKHI(v1, v0); o[3] = PACKHI(v3, v2);
    float s0 = r0 - __uint_as_float(v0 & 0xffff0000u);
    float s1 = r1 - __uint_as_float(v1 & 0xffff0000u);
    float s2 = r2 - __uint_as_float(v2 & 0xffff0000u);
    float s3 = r3 - __uint_as_float(v3 & 0xffff0000u);
    o[4] = PACKHI(__float_as_uint(s1), __float_as_uint(s0));
    o[5] = PACKHI(__float_as_uint(s3), __float_as_uint(s2));
}

__device__ __forceinline__ void decomp8(f32x4 a, f32x4 b,
                                        short8x* f0, short8x* f1, short8x* f2) {
    unsigned int oa[6], ob[6];
    decomp4(a, oa); decomp4(b, ob);
    uint4x t0 = {oa[0], oa[1], ob[0], ob[1]};
    uint4x t1 = {oa[2], oa[3], ob[2], ob[3]};
    uint4x t2 = {oa[4], oa[5], ob[4], ob[5]};
    *f0 = __builtin_bit_cast(short8x, t0);
    *f1 = __builtin_bit_cast(short8x, t1);
    *f2 = __builtin_bit_cast(short8x, t2);
}

// lgkm-only barrier: commit LDS ops, sync, leave global loads in flight
#define BARRIER() do { \
    asm volatile("s_waitcnt lgkmcnt(0)" ::: "memory"); \
    __builtin_amdgcn_s_barrier(); \
    __builtin_amdgcn_sched_barrier(0); \
} while (0)

#define STAGE_ISSUE(HA, HB, WA, WB, KOFF) do { \
    HA = *(const f32x4*)(hgsrc + (KOFF));     \
    HB = *(const f32x4*)(hgsrc + (KOFF) + 4); \
    WA = *(const f32x4*)(wgsrc + (KOFF));     \
    WB = *(const f32x4*)(wgsrc + (KOFF) + 4); \
} while (0)

#define STAGE_WRITE(HA, HB, WA, WB) do { \
    short8x f0_, f1_, f2_; \
    decomp8(HA, HB, &f0_, &f1_, &f2_); \
    *(short8x*)(ga + 0 * 4096 + soff) = f0_; \
    *(short8x*)(ga + 1 * 4096 + soff) = f1_; \
    *(short8x*)(ga + 2 * 4096 + soff) = f2_; \
    decomp8(WA, WB, &f0_, &f1_, &f2_); \
    *(short8x*)(ga + WL_OFF + 0 * 4096 + soff) = f0_; \
    *(short8x*)(ga + WL_OFF + 1 * 4096 + soff) = f1_; \
    *(short8x*)(ga + WL_OFF + 2 * 4096 + soff) = f2_; \
} while (0)

// wave = 32 tok x 32 exp = 2x2 16x16 tiles; 12 b128 reads feed 24 MFMAs.
// Per-tile MFMA order identical to the passing kernels (bit-identical tile partials).
#define COMPUTE() do { \
    const char* hb = ga; \
    const char* wb = ga + WL_OFF; \
    short8x a0[2], a1[2], a2[2]; \
    _Pragma("unroll") \
    for (int tt = 0; tt < 2; ++tt) { \
        const int t_ = wr * 32 + tt * 16 + l15; \
        const int ro_ = t_ * 64 + ((g ^ ((t_ >> 1) & 3)) << 4); \
        a0[tt] = *(const short8x*)(hb + 0 * 4096 + ro_); \
        a1[tt] = *(const short8x*)(hb + 1 * 4096 + ro_); \
        a2[tt] = *(const short8x*)(hb + 2 * 4096 + ro_); \
    } \
    _Pragma("unroll") \
    for (int et = 0; et < 2; ++et) { \
        const int e_ = wc * 32 + et * 16 + l15; \
        const int ro_ = e_ * 64 + ((g ^ ((e_ >> 1) & 3)) << 4); \
        short8x b0 = *(const short8x*)(wb + 0 * 4096 + ro_); \
        short8x b1 = *(const short8x*)(wb + 1 * 4096 + ro_); \
        short8x b2 = *(const short8x*)(wb + 2 * 4096 + ro_); \
        _Pragma("unroll") \
        for (int tt = 0; tt < 2; ++tt) { \
            Cm[tt][et] = __builtin_amdgcn_mfma_f32_16x16x32_bf16(a0[tt], b0, Cm[tt][et], 0, 0, 0); \
            Cc[tt][et] = __builtin_amdgcn_mfma_f32_16x16x32_bf16(a1[tt], b0, Cc[tt][et], 0, 0, 0); \
            Cc[tt][et] = __builtin_amdgcn_mfma_f32_16x16x32_bf16(a2[tt], b0, Cc[tt][et], 0, 0, 0); \
            Cc[tt][et] = __builtin_amdgcn_mfma_f32_16x16x32_bf16(a0[tt], b1, Cc[tt][et], 0, 0, 0); \
            Cc[tt][et] = __builtin_amdgcn_mfma_f32_16x16x32_bf16(a1[tt], b1, Cc[tt][et], 0, 0, 0); \
            Cc[tt][et] = __builtin_amdgcn_mfma_f32_16x16x32_bf16(a0[tt], b2, Cc[tt][et], 0, 0, 0); \
        } \
    } \
} while (0)

#define DRAIN do { \
    _Pragma("unroll") \
    for (int tt = 0; tt < 2; ++tt) \
        _Pragma("unroll") \
        for (int et = 0; et < 2; ++et) { \
            _Pragma("unroll") \
            for (int r = 0; r < 4; ++r) \
                md[tt][et][r] += (double)Cm[tt][et][r] + (double)Cc[tt][et][r]; \
            Cm[tt][et] = (f32x4)0.0f; Cc[tt][et] = (f32x4)0.0f; \
        } \
} while (0)

// 512 blocks x 512 threads (8 waves). Block = 64 tok x 64 exp, K split IN-BLOCK:
// waves 0-3 (grp 0) chunks 0..31, waves 4-7 (grp 1) chunks 32..63, each grp with its
// own single-buffered arena and the R9 rhythm (wave = 32x32, depth-2 reg prefetch).
// fp64 cross-group reduction via LDS at the end; epilogue identical to passing kernel.
__global__ __launch_bounds__(512, 4) void router_kernel(
    const float* __restrict__ H,
    const float* __restrict__ W,
    const float* __restrict__ B,
    float* __restrict__ out)
{
    __shared__ __align__(16) char arena[ARENA];
    float* bsf = (float*)(arena + BS_OFF);
    float* scf = (float*)(arena + SC_OFF);
    double* mdb = (double*)(arena + MD_OFF);

    const int tid  = threadIdx.x;
    const int lane = tid & 63;
    const int w    = __builtin_amdgcn_readfirstlane(tid >> 6);   // 0..7
    const int grp  = w >> 2;                                     // K-group (uniform)
    const int wl   = w & 3;                                      // wave within group
    const int l15  = lane & 15, g = lane >> 4;
    const size_t tb = (size_t)blockIdx.x * TOK;
    const int kbase = grp * KSEG;

    char* ga = arena + grp * GRP_ARENA;

    if (tid < NE) bsf[tid] = B[tid];

    // staging role within group: row = gtid>>2 (0..63), k-octet = gtid&3
    const int gtid = tid & 255;
    const int srow = gtid >> 2;
    const int sq   = gtid & 3;
    const float* hgsrc = H + (tb + (size_t)srow) * DIM + kbase + sq * 8;
    const float* wgsrc = W + (size_t)srow * DIM + kbase + sq * 8;
    const int soff = srow * 64 + ((sq ^ ((srow >> 1) & 3)) << 4);

    // compute role: wave quadrant (32 tok x 32 exp)
    const int wr = wl & 1, wc = wl >> 1;

    f32x4 Cm[2][2], Cc[2][2];
    double md[2][2][4];
    #pragma unroll
    for (int tt = 0; tt < 2; ++tt)
        #pragma unroll
        for (int et = 0; et < 2; ++et) {
            Cm[tt][et] = (f32x4)0.0f; Cc[tt][et] = (f32x4)0.0f;
            #pragma unroll
            for (int r = 0; r < 4; ++r) md[tt][et][r] = 0.0;
        }

    f32x4 hA0, hA1, wA0, wA1, hB0, hB1, wB0, wB1;

    // prologue: issue chunks 0,1 of this group; write chunk 0
    STAGE_ISSUE(hA0, hA1, wA0, wA1, 0);
    STAGE_ISSUE(hB0, hB1, wB0, wB1, KC);
    STAGE_WRITE(hA0, hA1, wA0, wA1);
    BARRIER();

    for (int chb = 0; chb < NCHG; chb += 2) {
        // even local chunk chb (in buf)
        COMPUTE();
        if (chb + 2 < NCHG) STAGE_ISSUE(hA0, hA1, wA0, wA1, (chb + 2) * KC);
        BARRIER();                                  // reads done
        STAGE_WRITE(hB0, hB1, wB0, wB1);            // local chunk chb+1 -> buf
        BARRIER();                                  // writes visible

        // odd local chunk chb+1
        COMPUTE();
        if (chb + 3 < NCHG) STAGE_ISSUE(hB0, hB1, wB0, wB1, (chb + 3) * KC);
        if (((chb + 1) & 7) == 7) DRAIN;            // local 7,15,23,31 (= global 8g+7)
        BARRIER();                                  // reads done
        if (chb + 2 < NCHG) STAGE_WRITE(hA0, hA1, wA0, wA1);
        BARRIER();                                  // writes visible
    }

    // cross-group fp64 reduction through LDS: grp1 writes, grp0 adds.
    // Symmetric threads (tid, tid+256) own identical (t,e) elements.
    if (grp == 1) {
        #pragma unroll
        for (int tt = 0; tt < 2; ++tt)
            #pragma unroll
            for (int et = 0; et < 2; ++et)
                #pragma unroll
                for (int r = 0; r < 4; ++r)
                    mdb[((tt * 2 + et) * 4 + r) * 256 + gtid] = md[tt][et][r];
    }
    __syncthreads();

    if (grp == 0) {
        #pragma unroll
        for (int tt = 0; tt < 2; ++tt)
            #pragma unroll
            for (int et = 0; et < 2; ++et)
                #pragma unroll
                for (int r = 0; r < 4; ++r) {
                    double m = md[tt][et][r] + mdb[((tt * 2 + et) * 4 + r) * 256 + gtid];
                    float s = 1.0f / (1.0f + expf(-(float)m));
                    int t = wr * 32 + tt * 16 + g * 4 + r;
                    int e = wc * 32 + et * 16 + l15;
                    scf[t * 65 + e] = s;
                }
    }
    __syncthreads();

    // grouped top-k, one token per active thread (64 tokens, threads in grp 0)
    if (tid < 256 && (tid & 3) == 0) {
        const int t = tid >> 2;
        const float* sc = &scf[t * 65];
        float gs[8];
        #pragma unroll
        for (int gg = 0; gg < 8; ++gg) {
            float m1 = -1e30f, m2 = -1e30f;
            #pragma unroll
            for (int j = 0; j < 8; ++j) {
                float v = sc[gg * 8 + j] + bsf[gg * 8 + j];
                if (v > m1) { m2 = m1; m1 = v; }
                else if (v > m2) { m2 = v; }
            }
            gs[gg] = m1 + m2;
        }
        unsigned gmask = 0;
        for (int i = 0; i < 4; ++i) {
            float best = -1e30f; int bg = 0;
            for (int gg = 0; gg < 8; ++gg)
                if (!((gmask >> gg) & 1u) && gs[gg] > best) { best = gs[gg]; bg = gg; }
            gmask |= 1u << bg;
        }
        unsigned long long picked = 0ull;
        int   idxs[8];
        float wts[8];
        float wsum = 0.0f;
        for (int i = 0; i < 8; ++i) {
            float best = -1e30f; int bi = 0;
            for (int e = 0; e < 64; ++e) {
                if ((picked >> e) & 1ull) continue;
                float v = ((gmask >> (e >> 3)) & 1u) ? (sc[e] + bsf[e]) : 0.0f;
                if (v > best) { best = v; bi = e; }
            }
            picked |= 1ull << bi;
            idxs[i] = bi;
            wts[i] = sc[bi];
            wsum += sc[bi];
        }
        const float scale = RSCALE / (wsum + REPS);
        const size_t token = tb + t;
        #pragma unroll
        for (int i = 0; i < 8; ++i) {
            out[token * 8 + i] = (float)idxs[i];
            out[(size_t)NT * 8 + token * 8 + i] = wts[i] * scale;
        }
    }
}

extern "C" void kernel_launch(void* const* d_in, const int* in_sizes, int n_in,
                              void* d_out, int out_size, void* d_ws, size_t ws_size,
                              hipStream_t stream) {
    (void)in_sizes; (void)n_in; (void)out_size; (void)d_ws; (void)ws_size;
    const float* H = (const float*)d_in[0];
    const float* W = (const float*)d_in[1];
    const float* B = (const float*)d_in[2];
    float* out = (float*)d_out;
    router_kernel<<<dim3(NT / TOK), dim3(512), 0, stream>>>(H, W, B, out);
}